// Round 11
// baseline (1255.311 us; speedup 1.0000x reference)
//
#include <hip/hip_runtime.h>

#define NT 128      // num tags
#define SEQ 1024    // sequence length
#define NB 256      // batch
#define NBLK 16     // blocks (CUs used)
#define BPB 16      // batches per block (= MFMA M)

typedef _Float16 half2v __attribute__((ext_vector_type(2)));
typedef _Float16 half8  __attribute__((ext_vector_type(8)));
typedef float    f32x4  __attribute__((ext_vector_type(4)));

// ---- DPP helpers (VALU pipe, no DS) ----
#define DPP_MAX_STEP(x, ctrl)                                                   \
    fmaxf((x), __builtin_bit_cast(float, __builtin_amdgcn_update_dpp(           \
        __builtin_bit_cast(int, (x)), __builtin_bit_cast(int, (x)),             \
        (ctrl), 0xf, 0xf, false)))
#define DPP_ADD_STEP(x, ctrl)                                                   \
    ((x) + __builtin_bit_cast(float, __builtin_amdgcn_update_dpp(               \
        0, __builtin_bit_cast(int, (x)), (ctrl), 0xf, 0xf, true)))

// within-16-lane reduce; lane 15 of each 16-row holds the result
__device__ __forceinline__ float max16_dpp(float x) {
    x = DPP_MAX_STEP(x, 0x111);   // row_shr:1
    x = DPP_MAX_STEP(x, 0x112);   // row_shr:2
    x = DPP_MAX_STEP(x, 0x114);   // row_shr:4
    x = DPP_MAX_STEP(x, 0x118);   // row_shr:8
    return x;
}
__device__ __forceinline__ float sum16_dpp(float x) {
    x = DPP_ADD_STEP(x, 0x111);
    x = DPP_ADD_STEP(x, 0x112);
    x = DPP_ADD_STEP(x, 0x114);
    x = DPP_ADD_STEP(x, 0x118);
    return x;
}
// lane[i^1] via DPP quad_perm [1,0,3,2] -- exact, VALU (R4-verified)
__device__ __forceinline__ float swap1_dpp(float x) {
    return __builtin_bit_cast(float, __builtin_amdgcn_update_dpp(
        0, __builtin_bit_cast(int, x), 0xB1, 0xf, 0xf, true));
}

// LDS-only barrier (R7-verified correct: absmax 0.0): drains DS pipe then
// s_barrier WITHOUT draining vmcnt -- the depth-1 emission ring loads stay
// in flight across the barrier (they have ~1 full step of slack; a
// __syncthreads vmcnt(0) drain would expose HBM latency every step here).
__device__ __forceinline__ void barrier_lds() {
    asm volatile("s_waitcnt lgkmcnt(0)\n\ts_barrier" ::: "memory");
}

__device__ __forceinline__ f32x4 mfma16(uint4 a, uint4 b, f32x4 c) {
    return __builtin_amdgcn_mfma_f32_16x16x32_f16(
        __builtin_bit_cast(half8, a), __builtin_bit_cast(half8, b), c, 0, 0, 0);
}

// Build one B-fragment (E = exp(transitions), f16) for tile T, K-chunk KC.
// u32 j holds f16 pair (k = KC*32 + lg*8 + 2j, k+1) -- the SAME k-bijection
// used when assembling A from LDS, which makes the MFMA contraction exact
// regardless of the HW's internal k ordering (dot products are k-permutation
// invariant when A and B share the packing).
#define BUILD_BF(dst, T, KC)                                                     \
    {                                                                            \
        const int ct_ = 32*w + 16*(T) + li;                                      \
        const int kb_ = (KC)*32 + lg*8;                                          \
        half2v h0_, h1_, h2_, h3_;                                               \
        h0_.x = (_Float16)__expf(transitions[(kb_+0)*NT + ct_]);                 \
        h0_.y = (_Float16)__expf(transitions[(kb_+1)*NT + ct_]);                 \
        h1_.x = (_Float16)__expf(transitions[(kb_+2)*NT + ct_]);                 \
        h1_.y = (_Float16)__expf(transitions[(kb_+3)*NT + ct_]);                 \
        h2_.x = (_Float16)__expf(transitions[(kb_+4)*NT + ct_]);                 \
        h2_.y = (_Float16)__expf(transitions[(kb_+5)*NT + ct_]);                 \
        h3_.x = (_Float16)__expf(transitions[(kb_+6)*NT + ct_]);                 \
        h3_.y = (_Float16)__expf(transitions[(kb_+7)*NT + ct_]);                 \
        dst.x = __builtin_bit_cast(unsigned int, h0_);                           \
        dst.y = __builtin_bit_cast(unsigned int, h1_);                           \
        dst.z = __builtin_bit_cast(unsigned int, h2_);                           \
        dst.w = __builtin_bit_cast(unsigned int, h3_);                           \
    }

// One scan step for 16 batches. Wave w owns N-cols [32w,32w+32) (2 tiles).
// A = P (16 batches x 128 tags, f16 pairs) read from swizzled LDS; C layout
// (verified m89): col = lane&15, row = 4*(lane>>4)+reg. Per-row (batch)
// rescale: v = C * exp(em) * inv[row]; masked select keeps old cur; row-max
// via 16-lane DPP -> cross-wave max via LDS; offset[row] += log(256*mx).
#define CRF_STEP(EMC, EMN, BUF, DO_PRE)                                          \
    {                                                                            \
        if (DO_PRE) {                                                            \
            _Pragma("unroll")                                                    \
            for (int j = 0; j < 8; ++j) {                                        \
                eoff[j] += NT;                                                   \
                EMN[j] = emissions[eoff[j]];                                     \
            }                                                                    \
        }                                                                        \
        const uint2 mw_ = *(const uint2*)&msk16[scur][4 * lg];                   \
        float xf_[8];                                                            \
        _Pragma("unroll")                                                        \
        for (int j = 0; j < 8; ++j) xf_[j] = __expf(EMC[j]);                     \
        const uint4 af0 = *(const uint4*)&p_lds[BUF][abase + (( 0 + lg*4) ^ swzA)]; \
        const uint4 af1 = *(const uint4*)&p_lds[BUF][abase + ((16 + lg*4) ^ swzA)]; \
        const uint4 af2 = *(const uint4*)&p_lds[BUF][abase + ((32 + lg*4) ^ swzA)]; \
        const uint4 af3 = *(const uint4*)&p_lds[BUF][abase + ((48 + lg*4) ^ swzA)]; \
        f32x4 c0_ = {0.f, 0.f, 0.f, 0.f};                                        \
        f32x4 c1_ = {0.f, 0.f, 0.f, 0.f};                                        \
        c0_ = mfma16(af0, bf00, c0_);  c1_ = mfma16(af0, bf10, c1_);             \
        c0_ = mfma16(af1, bf01, c0_);  c1_ = mfma16(af1, bf11, c1_);             \
        c0_ = mfma16(af2, bf02, c0_);  c1_ = mfma16(af2, bf12, c1_);             \
        c0_ = mfma16(af3, bf03, c0_);  c1_ = mfma16(af3, bf13, c1_);             \
        const unsigned int mlo_ = mw_.x, mhi_ = mw_.y;                           \
        _Pragma("unroll")                                                        \
        for (int r_ = 0; r_ < 4; ++r_) {                                         \
            const unsigned int mbits_ =                                          \
                (r_ == 0) ? (mlo_ & 0xffffu) : (r_ == 1) ? (mlo_ >> 16)          \
              : (r_ == 2) ? (mhi_ & 0xffffu) : (mhi_ >> 16);                     \
            const float v0_ = c0_[r_] * xf_[r_]     * inv[r_];                   \
            const float v1_ = c1_[r_] * xf_[4 + r_] * inv[r_];                   \
            if (mbits_ != 0u) {                                                  \
                cur0[r_] = v0_; cur1[r_] = v1_;                                  \
                offset[r_] += offadd[r_];                                        \
            }                                                                    \
        }                                                                        \
        _Pragma("unroll")                                                        \
        for (int r_ = 0; r_ < 4; ++r_) {                                         \
            const float p0o_ = swap1_dpp(cur0[r_]);                              \
            const float p1o_ = swap1_dpp(cur1[r_]);                              \
            if ((li & 1) == 0) {                                                 \
                const int b_ = 4 * lg + r_;                                      \
                const unsigned int sw_ = (unsigned int)((b_ & 7) << 2);          \
                p_lds[(BUF) ^ 1][b_*64 + ((unsigned int)kp0 ^ sw_)] =            \
                    __builtin_bit_cast(unsigned int,                             \
                        __builtin_amdgcn_cvt_pkrtz(cur0[r_], p0o_));             \
                p_lds[(BUF) ^ 1][b_*64 + ((unsigned int)(kp0 + 8) ^ sw_)] =      \
                    __builtin_bit_cast(unsigned int,                             \
                        __builtin_amdgcn_cvt_pkrtz(cur1[r_], p1o_));             \
            }                                                                    \
            const float rm_ = max16_dpp(fmaxf(cur0[r_], cur1[r_]));              \
            if (li == 15) wmax[(BUF) ^ 1][(4*lg + r_)*4 + w] = rm_;              \
        }                                                                        \
        barrier_lds();                                                           \
        _Pragma("unroll")                                                        \
        for (int r_ = 0; r_ < 4; ++r_) {                                         \
            const float4 wv_ = *(const float4*)&wmax[(BUF) ^ 1][(4*lg + r_)*4];  \
            const float mx_ = fmaxf(fmaxf(wv_.x, wv_.y), fmaxf(wv_.z, wv_.w));   \
            inv[r_] = __builtin_amdgcn_rcpf(256.0f * mx_);                       \
            offadd[r_] = __logf(mx_) + 5.545177444479562f;                       \
        }                                                                        \
        ++scur;                                                                  \
    }

// 16 blocks x 256 threads; block handles batches [16*blockIdx, +16) via
// MFMA (P 16x128 times E 128x128 per step). The scan is latency-bound, so
// concentrating 16 batches on one CU's matrix pipe cuts per-batch cost ~40x
// on the MAC side; renorm/exchange are amortized across 16 batches.
__global__ __launch_bounds__(256, 1) void crf_scan_kernel(
    const float* __restrict__ emissions,    // [B,S,T]
    const float* __restrict__ masks,        // [B,S]
    const int*   __restrict__ tags,         // [B,S]
    const float* __restrict__ transitions,  // [T,T] (log domain)
    const float* __restrict__ start_t,      // [T]
    const float* __restrict__ end_t,        // [T]
    float* __restrict__ out_per_batch)      // [B]
{
    const int b16 = blockIdx.x * BPB;
    const int tid = threadIdx.x;
    const int w   = tid >> 6;     // wave 0..3 (N-cols [32w, 32w+32))
    const int l   = tid & 63;
    const int li  = l & 15;       // A-row / B-col / C-col index
    const int lg  = l >> 4;       // lane group (k-group; C row base 4*lg)

    __shared__ __align__(16) unsigned int p_lds[2][16 * 64]; // P f16 pairs, swizzled
    __shared__ __align__(16) float wmax[2][64];              // [row][wave]
    __shared__ __align__(8)  _Float16 msk16[SEQ][BPB];       // masks, [s][batch]
    __shared__ __align__(16) float tsum_l[64];               // [row][wave]
    __shared__ float off_l[16], sc_l[16], sm_l[16];

    const int abase = li * 64;
    const unsigned int swzA = (unsigned int)((li & 7) << 2);
    const int kp0 = 16 * w + (li >> 1);

    // ---- E fragments (B-operand), 8x uint4 = 32 VGPRs ----
    uint4 bf00, bf01, bf02, bf03, bf10, bf11, bf12, bf13;
    BUILD_BF(bf00, 0, 0) BUILD_BF(bf01, 0, 1) BUILD_BF(bf02, 0, 2) BUILD_BF(bf03, 0, 3)
    BUILD_BF(bf10, 1, 0) BUILD_BF(bf11, 1, 1) BUILD_BF(bf12, 1, 2) BUILD_BF(bf13, 1, 3)

    // ---- stage masks as f16 [s][batch] (1 broadcast ds_read_b64/step) ----
    {
        const int bb = tid >> 4, s0 = tid & 15;
        const float* mp = masks + (size_t)(b16 + bb) * SEQ;
        for (int s = s0; s < SEQ; s += 16)
            msk16[s][bb] = (_Float16)mp[s];
    }

    // ---- P0 = exp(start) for every batch row (swizzled write) ----
    for (int u = tid; u < 16 * 64; u += 256) {
        const int b_ = u & 15, kp_ = u >> 4;
        const float e0 = __expf(start_t[2 * kp_]);
        const float e1 = __expf(start_t[2 * kp_ + 1]);
        p_lds[0][b_*64 + ((unsigned int)kp_ ^ (unsigned int)((b_ & 7) << 2))] =
            __builtin_bit_cast(unsigned int, __builtin_amdgcn_cvt_pkrtz(e0, e1));
    }

    // ---- per-lane state: cur (2 tiles x 4 rows), offsets, renorm ----
    float cur0[4], cur1[4], offset[4], inv[4], offadd[4];
    {
        const float cs0 = __expf(start_t[32 * w + li]);
        const float cs1 = __expf(start_t[32 * w + 16 + li]);
        #pragma unroll
        for (int r = 0; r < 4; ++r) {
            cur0[r] = cs0; cur1[r] = cs1; offset[r] = 0.f;
            const float rm = max16_dpp(fmaxf(cs0, cs1));
            if (li == 15) wmax[0][(4*lg + r)*4 + w] = rm;
        }
    }

    // ---- emission offsets: j = t*4 + reg -> (batch 4lg+reg, col 32w+16t+li)
    unsigned int eoff[8];
    #pragma unroll
    for (int j = 0; j < 8; ++j) {
        const int t_ = j >> 2, r_ = j & 3;
        eoff[j] = (unsigned int)(((b16 + 4*lg + r_) * SEQ) * NT + 32*w + 16*t_ + li);
    }

    __syncthreads();

    #pragma unroll
    for (int r = 0; r < 4; ++r) {
        const float4 wv = *(const float4*)&wmax[0][(4*lg + r)*4];
        const float mx = fmaxf(fmaxf(wv.x, wv.y), fmaxf(wv.z, wv.w));
        inv[r] = __builtin_amdgcn_rcpf(256.0f * mx);
        offadd[r] = __logf(mx) + 5.545177444479562f;   // log(256*mx)
    }

    float ema[8], emb[8];
    #pragma unroll
    for (int j = 0; j < 8; ++j) ema[j] = emissions[eoff[j]];   // prime s=0

    int scur = 0;
    for (int it = 0; it < (SEQ - 2) / 2; ++it) {   // steps 0..1021
        CRF_STEP(ema, emb, 0, true)
        CRF_STEP(emb, ema, 1, true)
    }
    CRF_STEP(ema, emb, 0, false)                   // step 1022
    CRF_STEP(emb, ema, 1, false)                   // step 1023

    // ---- log_z partials: sum_j cur[b][j]*exp(end[j]) ----
    {
        const float ee0 = __expf(end_t[32 * w + li]);
        const float ee1 = __expf(end_t[32 * w + 16 + li]);
        #pragma unroll
        for (int r = 0; r < 4; ++r) {
            float ts = cur0[r] * ee0 + cur1[r] * ee1;
            ts = sum16_dpp(ts);
            if (li == 15) tsum_l[(4*lg + r)*4 + w] = ts;
        }
        if (w == 0 && li == 15) {
            #pragma unroll
            for (int r = 0; r < 4; ++r) off_l[4*lg + r] = offset[r];
        }
    }
    __syncthreads();

    // ---- gold-path score: 16 threads per batch ----
    {
        const int bb = tid >> 4, sl = tid & 15;
        const int gb = b16 + bb;
        const float* ebb = emissions + (size_t)gb * SEQ * NT;
        const int tb = gb * SEQ;
        float sc = 0.f, sm = 0.f;
        for (int s = sl; s < SEQ; s += 16) {
            const float m = (float)msk16[s][bb];
            sm += m;
            if (s < SEQ - 1) {
                const int tg  = tags[tb + s];
                const int tg1 = tags[tb + s + 1];
                sc += ebb[(size_t)s * NT + tg] * m;
                sc += transitions[tg * NT + tg1] * (float)msk16[s + 1][bb];
            }
        }
        #pragma unroll
        for (int off = 8; off; off >>= 1) {
            sc += __shfl_xor(sc, off);
            sm += __shfl_xor(sm, off);
        }
        if (sl == 0) { sc_l[bb] = sc; sm_l[bb] = sm; }
    }
    __syncthreads();

    if (tid < 16) {
        const int r = tid;
        const int gb = b16 + r;
        const float4 tv = *(const float4*)&tsum_l[r * 4];
        const float log_z = off_l[r] + __logf((tv.x + tv.y) + (tv.z + tv.w));
        float sc = sc_l[r];
        const float smt = sm_l[r];
        const int tg0 = tags[gb * SEQ];
        const int tgl = tags[gb * SEQ + SEQ - 1];
        sc += start_t[tg0];
        const int last_ix = (int)fmaxf(smt - 1.0f, 0.0f);
        const float ml = (float)msk16[SEQ - 1][r];
        sc += emissions[((size_t)gb * SEQ + last_ix) * NT + tgl] * ml;
        sc += end_t[tgl] * ml;
        out_per_batch[gb] = log_z - sc;
    }
}

// mean over batch -> scalar output
__global__ void crf_reduce_kernel(const float* __restrict__ pb, float* __restrict__ out)
{
    float v = pb[threadIdx.x];   // 256 threads, one per batch
    #pragma unroll
    for (int off = 32; off; off >>= 1)
        v += __shfl_xor(v, off);
    __shared__ float s4[4];
    if ((threadIdx.x & 63) == 0) s4[threadIdx.x >> 6] = v;
    __syncthreads();
    if (threadIdx.x == 0)
        out[0] = (s4[0] + s4[1] + s4[2] + s4[3]) * (1.0f / 256.0f);
}

extern "C" void kernel_launch(void* const* d_in, const int* in_sizes, int n_in,
                              void* d_out, int out_size, void* d_ws, size_t ws_size,
                              hipStream_t stream) {
    const float* emissions   = (const float*)d_in[0];
    const float* masks       = (const float*)d_in[1];
    const int*   tags        = (const int*)  d_in[2];
    const float* transitions = (const float*)d_in[3];
    const float* start_t     = (const float*)d_in[4];
    const float* end_t       = (const float*)d_in[5];
    float* per_batch = (float*)d_ws;

    crf_scan_kernel<<<NBLK, 256, 0, stream>>>(emissions, masks, tags, transitions,
                                              start_t, end_t, per_batch);
    crf_reduce_kernel<<<1, 256, 0, stream>>>(per_batch, (float*)d_out);
}

// Round 12
// 898.634 us; speedup vs baseline: 1.3969x; 1.3969x over previous
//
#include <hip/hip_runtime.h>

#define NT 128      // num tags
#define SEQ 1024    // sequence length
#define NB 256      // batch
#define NBLK 16     // scan blocks (16 batches each)

typedef _Float16 half2v __attribute__((ext_vector_type(2)));
typedef _Float16 half8  __attribute__((ext_vector_type(8)));
typedef float    f32x4  __attribute__((ext_vector_type(4)));

// ---------------- shared helpers ----------------

#define DPP_MAX_STEP(x, ctrl)                                                   \
    fmaxf((x), __builtin_bit_cast(float, __builtin_amdgcn_update_dpp(           \
        __builtin_bit_cast(int, (x)), __builtin_bit_cast(int, (x)),             \
        (ctrl), 0xf, 0xf, false)))

__device__ __forceinline__ float wave_max_dpp(float x) {
    x = DPP_MAX_STEP(x, 0x111);
    x = DPP_MAX_STEP(x, 0x112);
    x = DPP_MAX_STEP(x, 0x114);
    x = DPP_MAX_STEP(x, 0x118);
    x = DPP_MAX_STEP(x, 0x142);
    x = DPP_MAX_STEP(x, 0x143);
    return __builtin_bit_cast(float, __builtin_amdgcn_readlane(
        __builtin_bit_cast(int, x), 63));
}

// lane[i] op lane[i^32] / lane[i^16] on the VALU (R5-verified bit-exact).
__device__ __forceinline__ float cross32_add(float x) {
    float a = x, b = x;
    asm volatile("v_permlane32_swap_b32 %0, %1" : "+v"(a), "+v"(b));
    return a + b;
}
__device__ __forceinline__ float cross16_add(float x) {
    float a = x, b = x;
    asm volatile("v_permlane16_swap_b32 %0, %1" : "+v"(a), "+v"(b));
    return a + b;
}
__device__ __forceinline__ float cross32_max(float x) {
    float a = x, b = x;
    asm volatile("v_permlane32_swap_b32 %0, %1" : "+v"(a), "+v"(b));
    return fmaxf(a, b);
}
__device__ __forceinline__ float cross16_max(float x) {
    float a = x, b = x;
    asm volatile("v_permlane16_swap_b32 %0, %1" : "+v"(a), "+v"(b));
    return fmaxf(a, b);
}
__device__ __forceinline__ float swap1_dpp(float x) {
    return __builtin_bit_cast(float, __builtin_amdgcn_update_dpp(
        0, __builtin_bit_cast(int, x), 0xB1, 0xf, 0xf, true));
}

__device__ __forceinline__ unsigned int pkrtz_u(float a, float b) {
    return __builtin_bit_cast(unsigned int, __builtin_amdgcn_cvt_pkrtz(a, b));
}
__device__ __forceinline__ f32x4 mfma16(uint4 a, uint4 b, f32x4 c) {
    return __builtin_amdgcn_mfma_f32_16x16x32_f16(
        __builtin_bit_cast(half8, a), __builtin_bit_cast(half8, b), c, 0, 0, 0);
}
__device__ __forceinline__ unsigned int packexp2(const float* p, int i0, int i1) {
    half2v h;
    h.x = (_Float16)__expf(p[i0]);
    h.y = (_Float16)__expf(p[i1]);
    return __builtin_bit_cast(unsigned int, h);
}

// ---------------- pre-pass: X = exp(emissions) as f16 pairs in scan order ----
// X[(b*SEQ+s)*64 + lg*16 + t*2 + i] = pack(exp(em[b][s][16t+4lg+2i]),
//                                          exp(em[b][s][16t+4lg+2i+1]))
__global__ void crf_preexp_kernel(const float* __restrict__ em,
                                  unsigned int* __restrict__ X) {
    const unsigned int total = (unsigned int)NB * SEQ * 64u;
    for (unsigned int o = blockIdx.x * blockDim.x + threadIdx.x; o < total;
         o += gridDim.x * blockDim.x) {
        const unsigned int bs  = o >> 6;
        const unsigned int w6  = o & 63u;
        const unsigned int lg_ = w6 >> 4;
        const unsigned int t_  = (w6 >> 1) & 7u;
        const unsigned int i_  = w6 & 1u;
        const unsigned int tag = 16u * t_ + 4u * lg_ + 2u * i_;
        const float2 e = *(const float2*)&em[(size_t)bs * NT + tag];
        half2v h;
        h.x = (_Float16)__expf(e.x);
        h.y = (_Float16)__expf(e.y);
        X[o] = __builtin_bit_cast(unsigned int, h);
    }
}

// ---------------- gold-path score (standalone, massively parallel) ----------
__global__ __launch_bounds__(256, 1) void crf_score_kernel(
    const float* __restrict__ emissions, const float* __restrict__ masks,
    const int* __restrict__ tags, const float* __restrict__ transitions,
    const float* __restrict__ start_t, const float* __restrict__ end_t,
    float* __restrict__ score_pb)
{
    const int b = blockIdx.x, tid = threadIdx.x;
    const int w = tid >> 6, l = tid & 63;
    __shared__ float msk_s[SEQ];
    __shared__ float redB[4], redC[4];
    for (int s = tid; s < SEQ; s += 256)
        msk_s[s] = masks[b * SEQ + s];
    __syncthreads();
    const float* eb = emissions + (size_t)b * SEQ * NT;
    const int tbase = b * SEQ;
    float sc = 0.0f, sm = 0.0f;
    for (int s = tid; s < SEQ; s += 256) {
        const float m = msk_s[s];
        sm += m;
        if (s < SEQ - 1) {
            const int tg  = tags[tbase + s];
            const int tg1 = tags[tbase + s + 1];
            sc += eb[(size_t)s * NT + tg] * m;
            sc += transitions[tg * NT + tg1] * msk_s[s + 1];
        }
    }
    #pragma unroll
    for (int off = 32; off; off >>= 1) {
        sc += __shfl_xor(sc, off);
        sm += __shfl_xor(sm, off);
    }
    if (l == 0) { redB[w] = sc; redC[w] = sm; }
    __syncthreads();
    if (tid == 0) {
        float sct = (redB[0] + redB[1]) + (redB[2] + redB[3]);
        float smt = (redC[0] + redC[1]) + (redC[2] + redC[3]);
        const int tg0 = tags[tbase];
        const int tgl = tags[tbase + SEQ - 1];
        sct += start_t[tg0];
        const int last_ix = (int)fmaxf(smt - 1.0f, 0.0f);
        const float ml = msk_s[SEQ - 1];
        sct += eb[(size_t)last_ix * NT + tgl] * ml;
        sct += end_t[tgl] * ml;
        score_pb[b] = sct;
    }
}

// ---------------- MFMA scan: 16 blocks x 1 wave, 16 batches/wave ------------
// alpha^T = E^T . P^T per step; k-bijection tau(lg,j) = 32kc+(j>=4)*16+4lg+(j&3)
// makes the C-output fragment (col=batch=lane&15, row=4*(lane>>4)+reg; m89/R11
// verified) IDENTICAL to the next step's B-operand fragment: B-frag(kc) =
// pk{A,B,C,D}[kc]. No LDS, no barriers, no P shuffles. Per-batch renorm max
// and the final sum cross only the 4 lane-groups at fixed li -> permlane
// swaps (R5-verified exact).

#define TILEPAIR(PK, RJ, CA, CB)                                                 \
    {                                                                            \
        const half2v h0_ = __builtin_bit_cast(half2v, RJ.x);                     \
        const half2v h1_ = __builtin_bit_cast(half2v, RJ.y);                     \
        const half2v h2_ = __builtin_bit_cast(half2v, RJ.z);                     \
        const half2v h3_ = __builtin_bit_cast(half2v, RJ.w);                     \
        const float v0_ = CA[0] * ((float)h0_.x * inv);                          \
        const float v1_ = CA[1] * ((float)h0_.y * inv);                          \
        const float v2_ = CA[2] * ((float)h1_.x * inv);                          \
        const float v3_ = CA[3] * ((float)h1_.y * inv);                          \
        const float v4_ = CB[0] * ((float)h2_.x * inv);                          \
        const float v5_ = CB[1] * ((float)h2_.y * inv);                          \
        const float v6_ = CB[2] * ((float)h3_.x * inv);                          \
        const float v7_ = CB[3] * ((float)h3_.y * inv);                          \
        PK.x = sel_ ? pkrtz_u(v0_, v1_) : PK.x;                                  \
        PK.y = sel_ ? pkrtz_u(v2_, v3_) : PK.y;                                  \
        PK.z = sel_ ? pkrtz_u(v4_, v5_) : PK.z;                                  \
        PK.w = sel_ ? pkrtz_u(v6_, v7_) : PK.w;                                  \
        tmax_ = fmaxf(tmax_, fmaxf(fmaxf(v0_, v1_), fmaxf(v2_, v3_)));           \
        tmax_ = fmaxf(tmax_, fmaxf(fmaxf(v4_, v5_), fmaxf(v6_, v7_)));           \
    }

#define SCAN_STEP(R0, R1, R2, R3, MV, MPRE, DO_PRE, POFF, MOFF)                  \
    {                                                                            \
        const float m_ = MV;                                                     \
        const bool sel_ = (m_ > 0.0f);                                           \
        f32x4 C[8];                                                              \
        _Pragma("unroll")                                                        \
        for (int t = 0; t < 8; ++t) { C[t][0]=0.f; C[t][1]=0.f; C[t][2]=0.f; C[t][3]=0.f; } \
        _Pragma("unroll")                                                        \
        for (int t = 0; t < 8; ++t) C[t] = mfma16(Af[t][0], pkA, C[t]);          \
        _Pragma("unroll")                                                        \
        for (int t = 0; t < 8; ++t) C[t] = mfma16(Af[t][1], pkB, C[t]);          \
        _Pragma("unroll")                                                        \
        for (int t = 0; t < 8; ++t) C[t] = mfma16(Af[t][2], pkC, C[t]);          \
        _Pragma("unroll")                                                        \
        for (int t = 0; t < 8; ++t) C[t] = mfma16(Af[t][3], pkD, C[t]);          \
        float tmax_ = -3.4e38f;                                                  \
        TILEPAIR(pkA, R0, C[0], C[1])                                            \
        TILEPAIR(pkB, R1, C[2], C[3])                                            \
        TILEPAIR(pkC, R2, C[4], C[5])                                            \
        TILEPAIR(pkD, R3, C[6], C[7])                                            \
        offset += sel_ ? offadd : 0.0f;                                          \
        const float am_ = cross32_max(cross16_max(tmax_));                       \
        mx = sel_ ? am_ : mx;                                                    \
        inv = __builtin_amdgcn_rcpf(256.0f * mx);                                \
        offadd = __logf(mx) + 5.545177444479562f;                                \
        if (DO_PRE) {                                                            \
            R0 = *(const uint4*)(xp + (POFF));                                   \
            R1 = *(const uint4*)(xp + (POFF) + 4);                               \
            R2 = *(const uint4*)(xp + (POFF) + 8);                               \
            R3 = *(const uint4*)(xp + (POFF) + 12);                              \
            MPRE = mp[MOFF];                                                     \
        }                                                                        \
    }

#define INITQ(PK, J)                                                             \
    {                                                                            \
        const int tb0 = 16 * (2 * (J)) + 4 * lg, tb1 = tb0 + 16;                 \
        const float a0 = __expf(start_t[tb0 + 0]), a1 = __expf(start_t[tb0 + 1]);\
        const float a2 = __expf(start_t[tb0 + 2]), a3 = __expf(start_t[tb0 + 3]);\
        const float b0 = __expf(start_t[tb1 + 0]), b1 = __expf(start_t[tb1 + 1]);\
        const float b2 = __expf(start_t[tb1 + 2]), b3 = __expf(start_t[tb1 + 3]);\
        PK.x = pkrtz_u(a0, a1); PK.y = pkrtz_u(a2, a3);                          \
        PK.z = pkrtz_u(b0, b1); PK.w = pkrtz_u(b2, b3);                          \
        tmax0 = fmaxf(tmax0, fmaxf(fmaxf(a0, a1), fmaxf(a2, a3)));               \
        tmax0 = fmaxf(tmax0, fmaxf(fmaxf(b0, b1), fmaxf(b2, b3)));               \
    }

#define TERMQ(PK, J)                                                             \
    {                                                                            \
        const half2v h0_ = __builtin_bit_cast(half2v, PK.x);                     \
        const half2v h1_ = __builtin_bit_cast(half2v, PK.y);                     \
        const half2v h2_ = __builtin_bit_cast(half2v, PK.z);                     \
        const half2v h3_ = __builtin_bit_cast(half2v, PK.w);                     \
        const int t0_ = 16 * (2 * (J)) + 4 * lg, t1_ = t0_ + 16;                 \
        eterm += (float)h0_.x * __expf(end_t[t0_ + 0]);                          \
        eterm += (float)h0_.y * __expf(end_t[t0_ + 1]);                          \
        eterm += (float)h1_.x * __expf(end_t[t0_ + 2]);                          \
        eterm += (float)h1_.y * __expf(end_t[t0_ + 3]);                          \
        eterm += (float)h2_.x * __expf(end_t[t1_ + 0]);                          \
        eterm += (float)h2_.y * __expf(end_t[t1_ + 1]);                          \
        eterm += (float)h3_.x * __expf(end_t[t1_ + 2]);                          \
        eterm += (float)h3_.y * __expf(end_t[t1_ + 3]);                          \
    }

__global__ __launch_bounds__(64, 1) void crf_mfma_scan_kernel(
    const unsigned int* __restrict__ X,     // pre-exp'd emissions (f16 pairs)
    const float* __restrict__ masks,
    const float* __restrict__ transitions,
    const float* __restrict__ start_t,
    const float* __restrict__ end_t,
    float* __restrict__ logz_pb)
{
    const int li  = threadIdx.x & 15;   // batch-col / A-row lane index
    const int lg  = threadIdx.x >> 4;   // lane group (k/row group)
    const int b16 = blockIdx.x * 16;

    // ---- A-operand: E^T fragments (128 VGPRs), tau-ordered ----
    uint4 Af[8][4];
    #pragma unroll
    for (int t = 0; t < 8; ++t) {
        const int col = 16 * t + li;
        #pragma unroll
        for (int kc = 0; kc < 4; ++kc) {
            const int kb = 32 * kc + 4 * lg;
            uint4 q;
            q.x = packexp2(transitions, (kb + 0)  * NT + col, (kb + 1)  * NT + col);
            q.y = packexp2(transitions, (kb + 2)  * NT + col, (kb + 3)  * NT + col);
            q.z = packexp2(transitions, (kb + 16) * NT + col, (kb + 17) * NT + col);
            q.w = packexp2(transitions, (kb + 18) * NT + col, (kb + 19) * NT + col);
            Af[t][kc] = q;
        }
    }

    // ---- init state: pk = pack(exp(start)), renorm from global max ----
    uint4 pkA, pkB, pkC, pkD;
    float tmax0 = -3.4e38f;
    INITQ(pkA, 0) INITQ(pkB, 1) INITQ(pkC, 2) INITQ(pkD, 3)
    float mx = cross32_max(cross16_max(tmax0));
    float inv = __builtin_amdgcn_rcpf(256.0f * mx);
    float offadd = __logf(mx) + 5.545177444479562f;   // log(256*mx)
    float offset = 0.0f;

    // ---- emission/mask rings (depth 2) ----
    const unsigned int* xp = X + ((size_t)(b16 + li) * SEQ) * 64 + lg * 16;
    const float* mp = masks + (size_t)(b16 + li) * SEQ;
    uint4 Ra0 = *(const uint4*)(xp + 0),  Ra1 = *(const uint4*)(xp + 4);
    uint4 Ra2 = *(const uint4*)(xp + 8),  Ra3 = *(const uint4*)(xp + 12);
    uint4 Rb0 = *(const uint4*)(xp + 64), Rb1 = *(const uint4*)(xp + 68);
    uint4 Rb2 = *(const uint4*)(xp + 72), Rb3 = *(const uint4*)(xp + 76);
    float mA = mp[0], mB = mp[1];

    for (int it = 0; it < (SEQ - 2) / 2; ++it) {      // steps 0..1021
        SCAN_STEP(Ra0, Ra1, Ra2, Ra3, mA, mA, true, 128, 2)
        SCAN_STEP(Rb0, Rb1, Rb2, Rb3, mB, mB, true, 192, 3)
        xp += 128;
        mp += 2;
    }
    SCAN_STEP(Ra0, Ra1, Ra2, Ra3, mA, mA, false, 0, 0)   // step 1022
    SCAN_STEP(Rb0, Rb1, Rb2, Rb3, mB, mB, false, 0, 0)   // step 1023

    // ---- log_z per batch (sum over tags = lane-local + cross-lg adds) ----
    float eterm = 0.0f;
    TERMQ(pkA, 0) TERMQ(pkB, 1) TERMQ(pkC, 2) TERMQ(pkD, 3)
    eterm = cross32_add(cross16_add(eterm));
    const float log_z = offset + __logf(eterm);
    if (lg == 0)
        logz_pb[b16 + li] = log_z;
}

// ---------------- reductions ----------------
__global__ void crf_reduce2_kernel(const float* __restrict__ logz,
                                   const float* __restrict__ score,
                                   float* __restrict__ out)
{
    float v = logz[threadIdx.x] - score[threadIdx.x];
    #pragma unroll
    for (int off = 32; off; off >>= 1)
        v += __shfl_xor(v, off);
    __shared__ float s4[4];
    if ((threadIdx.x & 63) == 0) s4[threadIdx.x >> 6] = v;
    __syncthreads();
    if (threadIdx.x == 0)
        out[0] = (s4[0] + s4[1] + s4[2] + s4[3]) * (1.0f / 256.0f);
}

__global__ void crf_reduce_kernel(const float* __restrict__ pb, float* __restrict__ out)
{
    float v = pb[threadIdx.x];
    #pragma unroll
    for (int off = 32; off; off >>= 1)
        v += __shfl_xor(v, off);
    __shared__ float s4[4];
    if ((threadIdx.x & 63) == 0) s4[threadIdx.x >> 6] = v;
    __syncthreads();
    if (threadIdx.x == 0)
        out[0] = (s4[0] + s4[1] + s4[2] + s4[3]) * (1.0f / 256.0f);
}

// ---------------- R4 fallback scan (verified best SIMT kernel) --------------
typedef _Float16 half2f __attribute__((ext_vector_type(2)));

#define CRF_STEP_FB(RC, RN, MC, DO_PRE, K, BUF)                                  \
    {                                                                            \
        float mcur = MC;                                                         \
        if (DO_PRE) { RC = emp[(K) * NT]; MC = mpp[K]; }                         \
        float eRN = __expf(RN);                                                  \
        const uint4* p4 = (const uint4*)&p_lds[BUF][ih * 32];                    \
        float A0=0.f, A1=0.f, A2=0.f, A3=0.f;                                    \
        _Pragma("unroll")                                                        \
        for (int qi = 0; qi < 8; ++qi) {                                         \
            uint4 q = p4[qi];                                                    \
            A0 = __builtin_amdgcn_fdot2(__builtin_bit_cast(half2f, q.x),         \
                                        E[4*qi+0], A0, false);                   \
            A1 = __builtin_amdgcn_fdot2(__builtin_bit_cast(half2f, q.y),         \
                                        E[4*qi+1], A1, false);                   \
            A2 = __builtin_amdgcn_fdot2(__builtin_bit_cast(half2f, q.z),         \
                                        E[4*qi+2], A2, false);                   \
            A3 = __builtin_amdgcn_fdot2(__builtin_bit_cast(half2f, q.w),         \
                                        E[4*qi+3], A3, false);                   \
        }                                                                        \
        float sv = cross32_add((A0 + A1) + (A2 + A3));                           \
        float v = sv * ex;                                                       \
        if (mcur > 0.0f) { cur = v; offset += offadd; }                          \
        float curo = swap1_dpp(cur);                                             \
        if (ih == 0 && (cl & 1) == 0)                                            \
            p_lds[(BUF)^1][16*w + (cl >> 1)] = pkrtz_u(cur, curo);               \
        float wm = wave_max_dpp(cur);                                            \
        if (l == 0) wmax[(BUF)^1][w] = wm;                                       \
        __syncthreads();                                                         \
        float4 wv = *(const float4*)&wmax[(BUF)^1][0];                           \
        mx = fmaxf(fmaxf(wv.x, wv.y), fmaxf(wv.z, wv.w));                        \
        inv = __builtin_amdgcn_rcpf(256.0f * mx);                                \
        offadd = __logf(mx) + 5.545177444479562f;                                \
        ex = eRN * inv;                                                          \
    }

__global__ __launch_bounds__(256, 1) void crf_scan_fallback(
    const float* __restrict__ emissions, const float* __restrict__ masks,
    const int* __restrict__ tags, const float* __restrict__ transitions,
    const float* __restrict__ start_t, const float* __restrict__ end_t,
    float* __restrict__ out_per_batch)
{
    const int b   = blockIdx.x;
    const int tid = threadIdx.x;
    const int w   = tid >> 6;
    const int l   = tid & 63;
    const int cl  = l & 31;
    const int ih  = l >> 5;
    const int c   = 32 * w + cl;
    const int i0  = 64 * ih;

    __shared__ __align__(16) unsigned int p_lds[2][64];
    __shared__ __align__(16) float        wmax[2][4];
    __shared__ float redA[4], redB[4], redC[4];
    __shared__ float msk_s[SEQ];

    half2f E[32];
    #pragma unroll
    for (int r = 0; r < 32; ++r) {
        float ea = transitions[(i0 + 2*r    ) * NT + c];
        float ob = transitions[(i0 + 2*r + 1) * NT + c];
        E[r] = half2f{(_Float16)__expf(ea), (_Float16)__expf(ob)};
    }
    for (int s = tid; s < SEQ; s += 256)
        msk_s[s] = masks[b * SEQ + s];

    float cur = __expf(start_t[c]);
    float offset = 0.0f;
    {
        float curo = swap1_dpp(cur);
        if (ih == 0 && (cl & 1) == 0)
            p_lds[0][16*w + (cl >> 1)] = pkrtz_u(cur, curo);
        float wm = wave_max_dpp(cur);
        if (l == 0) wmax[0][w] = wm;
    }
    __syncthreads();

    float4 wv0 = *(const float4*)&wmax[0][0];
    float mx   = fmaxf(fmaxf(wv0.x, wv0.y), fmaxf(wv0.z, wv0.w));
    float inv  = __builtin_amdgcn_rcpf(256.0f * mx);
    float offadd = __logf(mx) + 5.545177444479562f;

    const float* eb  = emissions + (size_t)b * SEQ * NT;
    const float* mkp = masks + b * SEQ;
    float ring0 = eb[(size_t)0 * NT + c];
    float ring1 = eb[(size_t)1 * NT + c];
    float ring2 = eb[(size_t)2 * NT + c];
    float ring3 = eb[(size_t)3 * NT + c];
    float mr0 = mkp[0], mr1 = mkp[1], mr2 = mkp[2], mr3 = mkp[3];
    float ex = __expf(ring0) * inv;
    const float* emp = eb + 4 * NT + c;
    const float* mpp = mkp + 4;

    for (int it = 0; it < (SEQ - 4) / 4; ++it) {
        CRF_STEP_FB(ring0, ring1, mr0, true, 0, 0)
        CRF_STEP_FB(ring1, ring2, mr1, true, 1, 1)
        CRF_STEP_FB(ring2, ring3, mr2, true, 2, 0)
        CRF_STEP_FB(ring3, ring0, mr3, true, 3, 1)
        emp += 4 * NT;
        mpp += 4;
    }
    CRF_STEP_FB(ring0, ring1, mr0, false, 0, 0)
    CRF_STEP_FB(ring1, ring2, mr1, false, 0, 1)
    CRF_STEP_FB(ring2, ring3, mr2, false, 0, 0)
    CRF_STEP_FB(ring3, ring3, mr3, false, 0, 1)

    float term = (ih == 0) ? cur * __expf(end_t[c]) : 0.0f;
    #pragma unroll
    for (int off = 32; off; off >>= 1)
        term += __shfl_xor(term, off);
    if (l == 0) redA[w] = term;

    const int tbase = b * SEQ;
    float sc = 0.0f, sm = 0.0f;
    for (int s = tid; s < SEQ; s += 256) {
        float m = msk_s[s];
        sm += m;
        if (s < SEQ - 1) {
            int tg  = tags[tbase + s];
            int tg1 = tags[tbase + s + 1];
            sc += eb[(size_t)s * NT + tg] * m;
            sc += transitions[tg * NT + tg1] * msk_s[s + 1];
        }
    }
    #pragma unroll
    for (int off = 32; off; off >>= 1) {
        sc += __shfl_xor(sc, off);
        sm += __shfl_xor(sm, off);
    }
    if (l == 0) { redB[w] = sc; redC[w] = sm; }
    __syncthreads();

    if (tid == 0) {
        float term_t = (redA[0] + redA[1]) + (redA[2] + redA[3]);
        float log_z  = offset + __logf(term_t);
        float sct    = (redB[0] + redB[1]) + (redB[2] + redB[3]);
        float smt    = (redC[0] + redC[1]) + (redC[2] + redC[3]);
        int tg0 = tags[tbase];
        int tgl = tags[tbase + SEQ - 1];
        sct += start_t[tg0];
        int last_ix = (int)fmaxf(smt - 1.0f, 0.0f);
        float ml = msk_s[SEQ - 1];
        sct += eb[(size_t)last_ix * NT + tgl] * ml;
        sct += end_t[tgl] * ml;
        out_per_batch[b] = log_z - sct;
    }
}

// ---------------- launch ----------------
extern "C" void kernel_launch(void* const* d_in, const int* in_sizes, int n_in,
                              void* d_out, int out_size, void* d_ws, size_t ws_size,
                              hipStream_t stream) {
    const float* emissions   = (const float*)d_in[0];
    const float* masks       = (const float*)d_in[1];
    const int*   tags        = (const int*)  d_in[2];
    const float* transitions = (const float*)d_in[3];
    const float* start_t     = (const float*)d_in[4];
    const float* end_t       = (const float*)d_in[5];

    const size_t X_BYTES = (size_t)NB * SEQ * 64 * 4;   // 64 MiB
    if (ws_size >= X_BYTES + 4096) {
        float* logz_pb  = (float*)d_ws;
        float* score_pb = logz_pb + 256;
        unsigned int* X = (unsigned int*)((char*)d_ws + 4096);
        crf_preexp_kernel<<<2048, 256, 0, stream>>>(emissions, X);
        crf_score_kernel<<<NB, 256, 0, stream>>>(emissions, masks, tags,
                                                 transitions, start_t, end_t, score_pb);
        crf_mfma_scan_kernel<<<NBLK, 64, 0, stream>>>(X, masks, transitions,
                                                      start_t, end_t, logz_pb);
        crf_reduce2_kernel<<<1, 256, 0, stream>>>(logz_pb, score_pb, (float*)d_out);
    } else {
        float* per_batch = (float*)d_ws;
        crf_scan_fallback<<<NB, 256, 0, stream>>>(emissions, masks, tags,
                                                  transitions, start_t, end_t, per_batch);
        crf_reduce_kernel<<<1, 256, 0, stream>>>(per_batch, (float*)d_out);
    }
}

// Round 13
// 558.034 us; speedup vs baseline: 2.2495x; 1.6104x over previous
//
#include <hip/hip_runtime.h>

#define NT 128      // num tags
#define SEQ 1024    // sequence length
#define NB 256      // batch

typedef _Float16 half2v __attribute__((ext_vector_type(2)));

// One DPP max step on the VALU pipe (no DS/lgkmcnt involvement).
#define DPP_MAX_STEP(x, ctrl)                                                   \
    fmaxf((x), __builtin_bit_cast(float, __builtin_amdgcn_update_dpp(           \
        __builtin_bit_cast(int, (x)), __builtin_bit_cast(int, (x)),             \
        (ctrl), 0xf, 0xf, false)))

__device__ __forceinline__ float wave_max_dpp(float x) {
    x = DPP_MAX_STEP(x, 0x111);   // row_shr:1
    x = DPP_MAX_STEP(x, 0x112);   // row_shr:2
    x = DPP_MAX_STEP(x, 0x114);   // row_shr:4
    x = DPP_MAX_STEP(x, 0x118);   // row_shr:8
    x = DPP_MAX_STEP(x, 0x142);   // row_bcast:15
    x = DPP_MAX_STEP(x, 0x143);   // row_bcast:31
    return __builtin_bit_cast(float, __builtin_amdgcn_readlane(
        __builtin_bit_cast(int, x), 63));
}

// lane[i] + lane[i^32] on the VALU pipe (v_permlane32_swap_b32, gfx950).
// With a=b=x, after the swap a+b == x[i&31] + x[(i&31)+32] in every lane.
__device__ __forceinline__ float cross32_add(float x) {
    float a = x, b = x;
    asm volatile("v_permlane32_swap_b32 %0, %1" : "+v"(a), "+v"(b));
    return a + b;
}

// lane[i^1] via DPP quad_perm [1,0,3,2] (ctrl 0xB1) -- VALU, exact.
__device__ __forceinline__ float swap1_dpp(float x) {
    return __builtin_bit_cast(float, __builtin_amdgcn_update_dpp(
        0, __builtin_bit_cast(int, x), 0xB1, 0xf, 0xf, true));
}

// One scan step, 4-wave cooperative version.
// Wave w owns columns [32w,32w+32); lane: col c=32w+(l&31), K-half ih=l>>5.
// P lives in LDS as packed f16 pairs (64 uints), double-buffered (BUF).
// One __syncthreads per step: reads of buffer BUF precede the barrier, the
// next step's writes target BUF^1 only after it (ping-pong, no 2nd barrier).
// All shuffle traffic (K-half combine, pack-partner exchange, wave max) is
// VALU (permlane/DPP); DS pipe carries only the cross-wave P/wmax exchange.
//
// SESSION LEDGER (final): this exact structure is the verified optimum of
// the R0-R12 exploration (436 us scan / 558 us total, absmax 0.0, -14.6%
// vs session start). Falsified alternatives, all measured:
//   - LDS->v_readlane broadcast (R1: flat; single-wave is issue-bound)
//   - lgkm-only barrier, 2 variants (R3/R7: flat/worse -- ring prefetches
//     land before the barrier; the vmcnt(0) drain was free)
//   - 8-wave split (R5: +22% -- fixed per-wave overhead duplicates, barrier
//     widens), 2-wave (R8: +27%), f32 pk_fma dots (R6: +98%, compiler
//     spills the 128-VGPR E array to scratch; VGPR_Count=88 proved it)
//   - DS-traffic halving + redundant per-wave f16 max (R9: +16% AND
//     absmax=64 -- DS-pipe-throughput theory falsified)
//   - MFMA restructures (R11: correct but 2620 cy/step, exchange-bound;
//     R12: 1630 cy/step one-wave chain AND absmax=64) -- matrix cores lose
//     on this recurrence: per-step chain latency exceeds R4's full step.
// The ~1000 cy/step cost is the serial dependence structure itself
// (barrier rendezvous + LDS turnaround + dependent dot/renorm chain);
// each component probed inelastic. NOT a HW roofline (HBM 2.5%, VALU 41%).
#define CRF_STEP(RC, RN, MC, DO_PRE, K, BUF)                                     \
    {                                                                            \
        float mcur = MC;                                                         \
        if (DO_PRE) { RC = emp[(K) * NT]; MC = mpp[K]; }                         \
        float eRN = __expf(RN);          /* hoisted off the post-barrier path */ \
        const uint4* p4 = (const uint4*)&p_lds[BUF][ih * 32];                    \
        float A0=0.f, A1=0.f, A2=0.f, A3=0.f;                                    \
        _Pragma("unroll")                                                        \
        for (int qi = 0; qi < 8; ++qi) {                                         \
            uint4 q = p4[qi];                                                    \
            A0 = __builtin_amdgcn_fdot2(__builtin_bit_cast(half2v, q.x),         \
                                        E[4*qi+0], A0, false);                   \
            A1 = __builtin_amdgcn_fdot2(__builtin_bit_cast(half2v, q.y),         \
                                        E[4*qi+1], A1, false);                   \
            A2 = __builtin_amdgcn_fdot2(__builtin_bit_cast(half2v, q.z),         \
                                        E[4*qi+2], A2, false);                   \
            A3 = __builtin_amdgcn_fdot2(__builtin_bit_cast(half2v, q.w),         \
                                        E[4*qi+3], A3, false);                   \
        }                                                                        \
        float sv = cross32_add((A0 + A1) + (A2 + A3));                           \
        float v = sv * ex;                                                       \
        if (mcur > 0.0f) { cur = v; offset += offadd; }                          \
        float curo = swap1_dpp(cur);     /* partner column for f16 pack */       \
        if (ih == 0 && (cl & 1) == 0)                                            \
            p_lds[(BUF)^1][16*w + (cl >> 1)] = __builtin_bit_cast(unsigned int,  \
                __builtin_amdgcn_cvt_pkrtz(cur, curo));                          \
        float wm = wave_max_dpp(cur);                                            \
        if (l == 0) wmax[(BUF)^1][w] = wm;                                       \
        __syncthreads();                                                         \
        float4 wv = *(const float4*)&wmax[(BUF)^1][0];                           \
        mx = fmaxf(fmaxf(wv.x, wv.y), fmaxf(wv.z, wv.w));                        \
        inv = __builtin_amdgcn_rcpf(256.0f * mx);                                \
        offadd = __logf(mx) + 5.545177444479562f;                                \
        ex = eRN * inv;                                                          \
    }

// FOUR WAVES per batch element (one per SIMD of a CU). 256 blocks x 256
// threads. The 128x128 matvec is split 4 ways; P and the per-wave maxes are
// exchanged through double-buffered LDS with one __syncthreads per step.
__global__ __launch_bounds__(256, 1) void crf_scan_kernel(
    const float* __restrict__ emissions,    // [B,S,T]
    const float* __restrict__ masks,        // [B,S]
    const int*   __restrict__ tags,         // [B,S]
    const float* __restrict__ transitions,  // [T,T] (log domain)
    const float* __restrict__ start_t,      // [T]
    const float* __restrict__ end_t,        // [T]
    float* __restrict__ out_per_batch)      // [B]
{
    const int b   = blockIdx.x;
    const int tid = threadIdx.x;
    const int w   = tid >> 6;     // wave 0..3
    const int l   = tid & 63;     // lane 0..63
    const int cl  = l & 31;       // column within wave
    const int ih  = l >> 5;       // which half of the i (row) range
    const int c   = 32 * w + cl;  // owned output column
    const int i0  = 64 * ih;      // start of this lane's i range

    __shared__ __align__(16) unsigned int p_lds[2][64]; // packed f16 P pairs
    __shared__ __align__(16) float        wmax[2][4];   // per-wave maxes
    __shared__ float redA[4], redB[4], redC[4];         // epilogue reductions
    __shared__ float msk_s[SEQ];

    // ---- E fragment: rows i0+2r, i0+2r+1 of column c, prob domain f16 ----
    half2v E[32];
    #pragma unroll
    for (int r = 0; r < 32; ++r) {
        float ea = transitions[(i0 + 2*r    ) * NT + c];
        float ob = transitions[(i0 + 2*r + 1) * NT + c];
        E[r] = half2v{(_Float16)__expf(ea), (_Float16)__expf(ob)};
    }

    for (int s = tid; s < SEQ; s += 256)
        msk_s[s] = masks[b * SEQ + s];

    // ---- init: P = exp(start), offset = 0 ----
    float cur = __expf(start_t[c]);
    float offset = 0.0f;

    {
        float curo = swap1_dpp(cur);
        if (ih == 0 && (cl & 1) == 0)
            p_lds[0][16*w + (cl >> 1)] = __builtin_bit_cast(unsigned int,
                __builtin_amdgcn_cvt_pkrtz(cur, curo));
        float wm = wave_max_dpp(cur);
        if (l == 0) wmax[0][w] = wm;
    }
    __syncthreads();

    float4 wv0 = *(const float4*)&wmax[0][0];
    float mx   = fmaxf(fmaxf(wv0.x, wv0.y), fmaxf(wv0.z, wv0.w));
    float inv  = __builtin_amdgcn_rcpf(256.0f * mx);
    float offadd = __logf(mx) + 5.545177444479562f;   // log(256*mx)

    const float* eb  = emissions + (size_t)b * SEQ * NT;
    const float* mkp = masks + b * SEQ;

    // depth-4 rings: slot k holds em/mask for step s with s&3==k (scalar)
    float ring0 = eb[(size_t)0 * NT + c];
    float ring1 = eb[(size_t)1 * NT + c];
    float ring2 = eb[(size_t)2 * NT + c];
    float ring3 = eb[(size_t)3 * NT + c];
    float mr0 = mkp[0], mr1 = mkp[1], mr2 = mkp[2], mr3 = mkp[3];

    float ex = __expf(ring0) * inv;

    const float* emp = eb + 4 * NT + c;   // em[s+4] for s=0
    const float* mpp = mkp + 4;

    // main loop: steps 0..1019, unrolled x4 (ring slots static; BUF = s&1)
    for (int it = 0; it < (SEQ - 4) / 4; ++it) {
        CRF_STEP(ring0, ring1, mr0, true, 0, 0)
        CRF_STEP(ring1, ring2, mr1, true, 1, 1)
        CRF_STEP(ring2, ring3, mr2, true, 2, 0)
        CRF_STEP(ring3, ring0, mr3, true, 3, 1)
        emp += 4 * NT;
        mpp += 4;
    }
    // tail: steps 1020..1023 (no prefetch)
    CRF_STEP(ring0, ring1, mr0, false, 0, 0)
    CRF_STEP(ring1, ring2, mr1, false, 0, 1)
    CRF_STEP(ring2, ring3, mr2, false, 0, 0)
    CRF_STEP(ring3, ring3, mr3, false, 0, 1)

    // ---- log_z = offset + log( sum_j P_j * exp(end_j) ) ----
    float term = (ih == 0) ? cur * __expf(end_t[c]) : 0.0f;
    #pragma unroll
    for (int off = 32; off; off >>= 1)
        term += __shfl_xor(term, off);
    if (l == 0) redA[w] = term;

    // ---- gold-path score (256 threads, 4 s-iters each) ----
    const int tbase = b * SEQ;
    float sc = 0.0f, sm = 0.0f;
    for (int s = tid; s < SEQ; s += 256) {
        float m = msk_s[s];
        sm += m;
        if (s < SEQ - 1) {
            int tg  = tags[tbase + s];
            int tg1 = tags[tbase + s + 1];
            sc += eb[(size_t)s * NT + tg] * m;
            sc += transitions[tg * NT + tg1] * msk_s[s + 1];
        }
    }
    #pragma unroll
    for (int off = 32; off; off >>= 1) {
        sc += __shfl_xor(sc, off);
        sm += __shfl_xor(sm, off);
    }
    if (l == 0) { redB[w] = sc; redC[w] = sm; }
    __syncthreads();

    if (tid == 0) {
        float term_t = (redA[0] + redA[1]) + (redA[2] + redA[3]);
        float log_z  = offset + __logf(term_t);
        float sct    = (redB[0] + redB[1]) + (redB[2] + redB[3]);
        float smt    = (redC[0] + redC[1]) + (redC[2] + redC[3]);
        int tg0 = tags[tbase];
        int tgl = tags[tbase + SEQ - 1];
        sct += start_t[tg0];
        int last_ix = (int)fmaxf(smt - 1.0f, 0.0f);
        float ml = msk_s[SEQ - 1];
        sct += eb[(size_t)last_ix * NT + tgl] * ml;
        sct += end_t[tgl] * ml;
        out_per_batch[b] = log_z - sct;
    }
}

// mean over batch -> scalar output
__global__ void crf_reduce_kernel(const float* __restrict__ pb, float* __restrict__ out)
{
    float v = pb[threadIdx.x];   // 256 threads, one per batch
    #pragma unroll
    for (int off = 32; off; off >>= 1)
        v += __shfl_xor(v, off);
    __shared__ float s4[4];
    if ((threadIdx.x & 63) == 0) s4[threadIdx.x >> 6] = v;
    __syncthreads();
    if (threadIdx.x == 0)
        out[0] = (s4[0] + s4[1] + s4[2] + s4[3]) * (1.0f / 256.0f);
}

extern "C" void kernel_launch(void* const* d_in, const int* in_sizes, int n_in,
                              void* d_out, int out_size, void* d_ws, size_t ws_size,
                              hipStream_t stream) {
    const float* emissions   = (const float*)d_in[0];
    const float* masks       = (const float*)d_in[1];
    const int*   tags        = (const int*)  d_in[2];
    const float* transitions = (const float*)d_in[3];
    const float* start_t     = (const float*)d_in[4];
    const float* end_t       = (const float*)d_in[5];
    float* per_batch = (float*)d_ws;

    crf_scan_kernel<<<NB, 256, 0, stream>>>(emissions, masks, tags, transitions,
                                            start_t, end_t, per_batch);
    crf_reduce_kernel<<<1, 256, 0, stream>>>(per_batch, (float*)d_out);
}

// Round 15
// 555.940 us; speedup vs baseline: 2.2580x; 1.0038x over previous
//
#include <hip/hip_runtime.h>

#define NT 128      // num tags
#define SEQ 1024    // sequence length
#define NB 256      // batch

typedef _Float16 half2v __attribute__((ext_vector_type(2)));

// One DPP max step on the VALU pipe (no DS/lgkmcnt involvement).
#define DPP_MAX_STEP(x, ctrl)                                                   \
    fmaxf((x), __builtin_bit_cast(float, __builtin_amdgcn_update_dpp(           \
        __builtin_bit_cast(int, (x)), __builtin_bit_cast(int, (x)),             \
        (ctrl), 0xf, 0xf, false)))

__device__ __forceinline__ float wave_max_dpp(float x) {
    x = DPP_MAX_STEP(x, 0x111);   // row_shr:1
    x = DPP_MAX_STEP(x, 0x112);   // row_shr:2
    x = DPP_MAX_STEP(x, 0x114);   // row_shr:4
    x = DPP_MAX_STEP(x, 0x118);   // row_shr:8
    x = DPP_MAX_STEP(x, 0x142);   // row_bcast:15
    x = DPP_MAX_STEP(x, 0x143);   // row_bcast:31
    return __builtin_bit_cast(float, __builtin_amdgcn_readlane(
        __builtin_bit_cast(int, x), 63));
}

// lane[i] + lane[i^32] on the VALU pipe (v_permlane32_swap_b32, gfx950).
// With a=b=x, after the swap a+b == x[i&31] + x[(i&31)+32] in every lane.
__device__ __forceinline__ float cross32_add(float x) {
    float a = x, b = x;
    asm volatile("v_permlane32_swap_b32 %0, %1" : "+v"(a), "+v"(b));
    return a + b;
}

// lane[i^1] via DPP quad_perm [1,0,3,2] (ctrl 0xB1) -- VALU, exact.
__device__ __forceinline__ float swap1_dpp(float x) {
    return __builtin_bit_cast(float, __builtin_amdgcn_update_dpp(
        0, __builtin_bit_cast(int, x), 0xB1, 0xf, 0xf, true));
}

// One scan step, 4-wave cooperative version.
// Wave w owns columns [32w,32w+32); lane: col c=32w+(l&31), K-half ih=l>>5.
// P lives in LDS as packed f16 pairs (64 uints), double-buffered (BUF).
// One __syncthreads per step: reads of buffer BUF precede the barrier, the
// next step's writes target BUF^1 only after it (ping-pong, no 2nd barrier).
// All shuffle traffic (K-half combine, pack-partner exchange, wave max) is
// VALU (permlane/DPP); DS pipe carries only the cross-wave P/wmax exchange.
//
// SESSION LEDGER (final): this structure is the verified optimum of the
// R0-R14 exploration (436 us scan, absmax 0.0, reproduced 3x; -15% total
// vs session start). Falsified/failed alternatives, all measured:
//   - LDS->v_readlane broadcast (R1: flat; single-wave is issue-bound)
//   - lgkm-only barrier, 2 variants (R3/R7: flat/worse -- ring prefetches
//     land before the barrier; the vmcnt(0) drain was free)
//   - 8-wave split (R5: +22%), 2-wave (R8: +27%) -- fixed per-wave overhead
//     duplicates and the barrier widens with wave count
//   - f32 pk_fma dots (R6: +98%, compiler spilled the 128-VGPR E array;
//     VGPR_Count=88 proved it)
//   - DS-traffic halving + per-wave redundant f16 max (R9: +16%, passed
//     at absmax=64 -- DS-pipe-throughput theory falsified)
//   - MFMA restructures (R11: correct, 2.6x slower, exchange-bound;
//     R12: exchange-free variant, 1.6x slower + absmax drift) -- the
//     per-step MFMA chain latency exceeds this kernel's whole step
//   - 2-batch ILP-fill in one block (R14: unexplained absmax=160 FAIL;
//     mechanism never identified -- do not re-roll without a theory)
// The ~1000 cy/step cost is the serial dependence structure itself
// (barrier rendezvous + LDS turnaround + dependent dot/renorm chain);
// each component probed inelastic. NOT a HW roofline (HBM 2.5%, VALU 41%).
#define CRF_STEP(RC, RN, MC, DO_PRE, K, BUF)                                     \
    {                                                                            \
        float mcur = MC;                                                         \
        if (DO_PRE) { RC = emp[(K) * NT]; MC = mpp[K]; }                         \
        float eRN = __expf(RN);          /* hoisted off the post-barrier path */ \
        const uint4* p4 = (const uint4*)&p_lds[BUF][ih * 32];                    \
        float A0=0.f, A1=0.f, A2=0.f, A3=0.f;                                    \
        _Pragma("unroll")                                                        \
        for (int qi = 0; qi < 8; ++qi) {                                         \
            uint4 q = p4[qi];                                                    \
            A0 = __builtin_amdgcn_fdot2(__builtin_bit_cast(half2v, q.x),         \
                                        E[4*qi+0], A0, false);                   \
            A1 = __builtin_amdgcn_fdot2(__builtin_bit_cast(half2v, q.y),         \
                                        E[4*qi+1], A1, false);                   \
            A2 = __builtin_amdgcn_fdot2(__builtin_bit_cast(half2v, q.z),         \
                                        E[4*qi+2], A2, false);                   \
            A3 = __builtin_amdgcn_fdot2(__builtin_bit_cast(half2v, q.w),         \
                                        E[4*qi+3], A3, false);                   \
        }                                                                        \
        float sv = cross32_add((A0 + A1) + (A2 + A3));                           \
        float v = sv * ex;                                                       \
        if (mcur > 0.0f) { cur = v; offset += offadd; }                          \
        float curo = swap1_dpp(cur);     /* partner column for f16 pack */       \
        if (ih == 0 && (cl & 1) == 0)                                            \
            p_lds[(BUF)^1][16*w + (cl >> 1)] = __builtin_bit_cast(unsigned int,  \
                __builtin_amdgcn_cvt_pkrtz(cur, curo));                          \
        float wm = wave_max_dpp(cur);                                            \
        if (l == 0) wmax[(BUF)^1][w] = wm;                                       \
        __syncthreads();                                                         \
        float4 wv = *(const float4*)&wmax[(BUF)^1][0];                           \
        mx = fmaxf(fmaxf(wv.x, wv.y), fmaxf(wv.z, wv.w));                        \
        inv = __builtin_amdgcn_rcpf(256.0f * mx);                                \
        offadd = __logf(mx) + 5.545177444479562f;                                \
        ex = eRN * inv;                                                          \
    }

// FOUR WAVES per batch element (one per SIMD of a CU). 256 blocks x 256
// threads. The 128x128 matvec is split 4 ways; P and the per-wave maxes are
// exchanged through double-buffered LDS with one __syncthreads per step.
// The batch-mean is fused here via one f32 atomicAdd per block (the harness
// zeroes d_out before each launch), deleting the separate reduce dispatch.
__global__ __launch_bounds__(256, 1) void crf_scan_kernel(
    const float* __restrict__ emissions,    // [B,S,T]
    const float* __restrict__ masks,        // [B,S]
    const int*   __restrict__ tags,         // [B,S]
    const float* __restrict__ transitions,  // [T,T] (log domain)
    const float* __restrict__ start_t,      // [T]
    const float* __restrict__ end_t,        // [T]
    float* __restrict__ out_mean)           // [1], pre-zeroed by harness
{
    const int b   = blockIdx.x;
    const int tid = threadIdx.x;
    const int w   = tid >> 6;     // wave 0..3
    const int l   = tid & 63;     // lane 0..63
    const int cl  = l & 31;       // column within wave
    const int ih  = l >> 5;       // which half of the i (row) range
    const int c   = 32 * w + cl;  // owned output column
    const int i0  = 64 * ih;      // start of this lane's i range

    __shared__ __align__(16) unsigned int p_lds[2][64]; // packed f16 P pairs
    __shared__ __align__(16) float        wmax[2][4];   // per-wave maxes
    __shared__ float redA[4], redB[4], redC[4];         // epilogue reductions
    __shared__ float msk_s[SEQ];

    // ---- E fragment: rows i0+2r, i0+2r+1 of column c, prob domain f16 ----
    half2v E[32];
    #pragma unroll
    for (int r = 0; r < 32; ++r) {
        float ea = transitions[(i0 + 2*r    ) * NT + c];
        float ob = transitions[(i0 + 2*r + 1) * NT + c];
        E[r] = half2v{(_Float16)__expf(ea), (_Float16)__expf(ob)};
    }

    for (int s = tid; s < SEQ; s += 256)
        msk_s[s] = masks[b * SEQ + s];

    // ---- init: P = exp(start), offset = 0 ----
    float cur = __expf(start_t[c]);
    float offset = 0.0f;

    {
        float curo = swap1_dpp(cur);
        if (ih == 0 && (cl & 1) == 0)
            p_lds[0][16*w + (cl >> 1)] = __builtin_bit_cast(unsigned int,
                __builtin_amdgcn_cvt_pkrtz(cur, curo));
        float wm = wave_max_dpp(cur);
        if (l == 0) wmax[0][w] = wm;
    }
    __syncthreads();

    float4 wv0 = *(const float4*)&wmax[0][0];
    float mx   = fmaxf(fmaxf(wv0.x, wv0.y), fmaxf(wv0.z, wv0.w));
    float inv  = __builtin_amdgcn_rcpf(256.0f * mx);
    float offadd = __logf(mx) + 5.545177444479562f;   // log(256*mx)

    const float* eb  = emissions + (size_t)b * SEQ * NT;
    const float* mkp = masks + b * SEQ;

    // depth-4 rings: slot k holds em/mask for step s with s&3==k (scalar)
    float ring0 = eb[(size_t)0 * NT + c];
    float ring1 = eb[(size_t)1 * NT + c];
    float ring2 = eb[(size_t)2 * NT + c];
    float ring3 = eb[(size_t)3 * NT + c];
    float mr0 = mkp[0], mr1 = mkp[1], mr2 = mkp[2], mr3 = mkp[3];

    float ex = __expf(ring0) * inv;

    const float* emp = eb + 4 * NT + c;   // em[s+4] for s=0
    const float* mpp = mkp + 4;

    // main loop: steps 0..1019, unrolled x4 (ring slots static; BUF = s&1)
    for (int it = 0; it < (SEQ - 4) / 4; ++it) {
        CRF_STEP(ring0, ring1, mr0, true, 0, 0)
        CRF_STEP(ring1, ring2, mr1, true, 1, 1)
        CRF_STEP(ring2, ring3, mr2, true, 2, 0)
        CRF_STEP(ring3, ring0, mr3, true, 3, 1)
        emp += 4 * NT;
        mpp += 4;
    }
    // tail: steps 1020..1023 (no prefetch)
    CRF_STEP(ring0, ring1, mr0, false, 0, 0)
    CRF_STEP(ring1, ring2, mr1, false, 0, 1)
    CRF_STEP(ring2, ring3, mr2, false, 0, 0)
    CRF_STEP(ring3, ring3, mr3, false, 0, 1)

    // ---- log_z = offset + log( sum_j P_j * exp(end_j) ) ----
    float term = (ih == 0) ? cur * __expf(end_t[c]) : 0.0f;
    #pragma unroll
    for (int off = 32; off; off >>= 1)
        term += __shfl_xor(term, off);
    if (l == 0) redA[w] = term;

    // ---- gold-path score (256 threads, 4 s-iters each) ----
    const int tbase = b * SEQ;
    float sc = 0.0f, sm = 0.0f;
    for (int s = tid; s < SEQ; s += 256) {
        float m = msk_s[s];
        sm += m;
        if (s < SEQ - 1) {
            int tg  = tags[tbase + s];
            int tg1 = tags[tbase + s + 1];
            sc += eb[(size_t)s * NT + tg] * m;
            sc += transitions[tg * NT + tg1] * msk_s[s + 1];
        }
    }
    #pragma unroll
    for (int off = 32; off; off >>= 1) {
        sc += __shfl_xor(sc, off);
        sm += __shfl_xor(sm, off);
    }
    if (l == 0) { redB[w] = sc; redC[w] = sm; }
    __syncthreads();

    if (tid == 0) {
        float term_t = (redA[0] + redA[1]) + (redA[2] + redA[3]);
        float log_z  = offset + __logf(term_t);
        float sct    = (redB[0] + redB[1]) + (redB[2] + redB[3]);
        float smt    = (redC[0] + redC[1]) + (redC[2] + redC[3]);
        int tg0 = tags[tbase];
        int tgl = tags[tbase + SEQ - 1];
        sct += start_t[tg0];
        int last_ix = (int)fmaxf(smt - 1.0f, 0.0f);
        float ml = msk_s[SEQ - 1];
        sct += eb[(size_t)last_ix * NT + tgl] * ml;
        sct += end_t[tgl] * ml;
        // fused batch-mean: device-scope f32 atomic (G12); harness pre-zeroes
        atomicAdd(out_mean, (log_z - sct) * (1.0f / 256.0f));
    }
}

extern "C" void kernel_launch(void* const* d_in, const int* in_sizes, int n_in,
                              void* d_out, int out_size, void* d_ws, size_t ws_size,
                              hipStream_t stream) {
    const float* emissions   = (const float*)d_in[0];
    const float* masks       = (const float*)d_in[1];
    const int*   tags        = (const int*)  d_in[2];
    const float* transitions = (const float*)d_in[3];
    const float* start_t     = (const float*)d_in[4];
    const float* end_t       = (const float*)d_in[5];

    crf_scan_kernel<<<NB, 256, 0, stream>>>(emissions, masks, tags, transitions,
                                            start_t, end_t, (float*)d_out);
}